// Round 1
// baseline (592.782 us; speedup 1.0000x reference)
//
#include <hip/hip_runtime.h>
#include <math.h>

#define D 1280
#define NST 20
#define MTRI 190
#define NTOK 8192   // B*L

// ---------------- Kernel A: H = gelu(hx @ dense_w + dense_b) ----------------
#define BM 128
#define BN 128
#define BK 16
#define LDP (BM + 4)   // padded LDS stride (132 floats = 528B, 16B-aligned)

__global__ __launch_bounds__(256) void gemm_gelu_kernel(
    const float* __restrict__ A,    // [NTOK, D]
    const float* __restrict__ Bw,   // [D, D]
    const float* __restrict__ bias, // [D]
    float* __restrict__ H)          // [NTOK, D]
{
    __shared__ float As[BK][LDP];
    __shared__ float Bs[BK][LDP];

    const int tid  = threadIdx.x;
    const int row0 = blockIdx.x * BM;
    const int col0 = blockIdx.y * BN;

    const int tx = tid & 15;   // 0..15 -> N
    const int ty = tid >> 4;   // 0..15 -> M

    float acc[8][8];
#pragma unroll
    for (int i = 0; i < 8; ++i)
#pragma unroll
        for (int j = 0; j < 8; ++j) acc[i][j] = 0.0f;

    const int aRow = tid >> 2;          // 0..63
    const int aCol = (tid & 3) * 4;     // 0,4,8,12
    const int bRow = tid >> 5;          // 0..7
    const int bCol = (tid & 31) * 4;    // 0..124

    for (int k0 = 0; k0 < D; k0 += BK) {
        // load A tile (BM x BK), store transposed
#pragma unroll
        for (int p = 0; p < 2; ++p) {
            int r = aRow + p * 64;
            float4 v = *(const float4*)&A[(size_t)(row0 + r) * D + k0 + aCol];
            As[aCol + 0][r] = v.x;
            As[aCol + 1][r] = v.y;
            As[aCol + 2][r] = v.z;
            As[aCol + 3][r] = v.w;
        }
        // load B tile (BK x BN)
#pragma unroll
        for (int p = 0; p < 2; ++p) {
            int r = bRow + p * 8;
            float4 v = *(const float4*)&Bw[(size_t)(k0 + r) * D + col0 + bCol];
            *(float4*)&Bs[r][bCol] = v;
        }
        __syncthreads();

#pragma unroll
        for (int k = 0; k < BK; ++k) {
            float4 a0 = *(const float4*)&As[k][ty * 8];
            float4 a1 = *(const float4*)&As[k][ty * 8 + 4];
            float4 b0 = *(const float4*)&Bs[k][tx * 8];
            float4 b1 = *(const float4*)&Bs[k][tx * 8 + 4];
            float av[8] = {a0.x, a0.y, a0.z, a0.w, a1.x, a1.y, a1.z, a1.w};
            float bv[8] = {b0.x, b0.y, b0.z, b0.w, b1.x, b1.y, b1.z, b1.w};
#pragma unroll
            for (int i = 0; i < 8; ++i)
#pragma unroll
                for (int j = 0; j < 8; ++j) acc[i][j] += av[i] * bv[j];
        }
        __syncthreads();
    }

    // epilogue: bias + exact gelu, vectorized store
#pragma unroll
    for (int i = 0; i < 8; ++i) {
        int row = row0 + ty * 8 + i;
        float out[8];
#pragma unroll
        for (int j = 0; j < 8; ++j) {
            float h = acc[i][j] + bias[col0 + tx * 8 + j];
            out[j] = 0.5f * h * (1.0f + erff(h * 0.70710678118654752f));
        }
        float* dst = &H[(size_t)row * D + col0 + tx * 8];
        *(float4*)(dst + 0) = make_float4(out[0], out[1], out[2], out[3]);
        *(float4*)(dst + 4) = make_float4(out[4], out[5], out[6], out[7]);
    }
}

// ---------------- Kernel B: LN + logits + softmax/softplus + Q assembly -----
// 8 rows per block, 256 threads (4 waves; wave w owns rows 2w, 2w+1 for LN).
__global__ __launch_bounds__(256) void head_kernel(
    const float* __restrict__ H,
    const float* __restrict__ ln_w, const float* __restrict__ ln_b,
    const float* __restrict__ theta_w, const float* __restrict__ theta_b,
    const float* __restrict__ Theta_w, const float* __restrict__ Theta_b,
    float* __restrict__ Out)
{
    __shared__ float hn[8][D];        // 40 KB normalized rows
    __shared__ float th_l[8][NST];    // raw theta logits
    __shared__ float sp_l[8][MTRI];   // softplus(Theta logits)
    __shared__ float s_l[8][NST];     // sqrt(pi)

    const int tid  = threadIdx.x;
    const int lane = tid & 63;
    const int wave = tid >> 6;
    const int g0   = blockIdx.x * 8;

    // ---- Phase 1: LayerNorm (per wave: 2 rows) ----
#pragma unroll
    for (int rr = 0; rr < 2; ++rr) {
        const int r = wave * 2 + rr;
        const float* src = H + (size_t)(g0 + r) * D;
        float x[20];
        float sum = 0.f, sq = 0.f;
#pragma unroll
        for (int it = 0; it < 20; ++it) {
            float v = src[lane + it * 64];
            x[it] = v; sum += v; sq += v * v;
        }
#pragma unroll
        for (int off = 1; off < 64; off <<= 1) {
            sum += __shfl_xor(sum, off);
            sq  += __shfl_xor(sq, off);
        }
        const float mean = sum * (1.0f / D);
        const float var  = sq * (1.0f / D) - mean * mean;
        const float inv  = rsqrtf(var + 1e-5f);
#pragma unroll
        for (int it = 0; it < 20; ++it) {
            int k = lane + it * 64;
            hn[r][k] = (x[it] - mean) * inv * ln_w[k] + ln_b[k];
        }
    }
    __syncthreads();

    // ---- Phase 2: logits (one column per thread, 210 active) ----
    if (tid < NST + MTRI) {
        const bool isTheta = tid >= NST;
        const int  col     = isTheta ? (tid - NST) : tid;
        const float* W     = isTheta ? (Theta_w + col) : (theta_w + col);
        const int  stride  = isTheta ? MTRI : NST;

        float acc[8] = {0, 0, 0, 0, 0, 0, 0, 0};
        for (int k = 0; k < D; k += 4) {
            float w0 = W[(size_t)(k + 0) * stride];
            float w1 = W[(size_t)(k + 1) * stride];
            float w2 = W[(size_t)(k + 2) * stride];
            float w3 = W[(size_t)(k + 3) * stride];
#pragma unroll
            for (int r = 0; r < 8; ++r) {
                float4 h4 = *(const float4*)&hn[r][k];
                acc[r] += h4.x * w0 + h4.y * w1 + h4.z * w2 + h4.w * w3;
            }
        }
        const float bias = isTheta ? Theta_b[col] : theta_b[col];
#pragma unroll
        for (int r = 0; r < 8; ++r) {
            float v = acc[r] + bias;
            if (isTheta) {
                sp_l[r][col] = (v > 20.0f) ? v : log1pf(expf(v));
            } else {
                th_l[r][col] = v;
            }
        }
    }
    __syncthreads();

    // ---- Phase 3a: softmax -> sqrt(pi), per half-wave row ----
    {
        const int half = lane >> 5;
        const int l    = lane & 31;
        const int r    = wave * 2 + half;
        float v = (l < NST) ? th_l[r][l] : -1e30f;
        float m = v;
#pragma unroll
        for (int off = 16; off >= 1; off >>= 1) m = fmaxf(m, __shfl_xor(m, off));
        float e = (l < NST) ? __expf(v - m) : 0.0f;
        float s = e;
#pragma unroll
        for (int off = 16; off >= 1; off >>= 1) s += __shfl_xor(s, off);
        if (l < NST) s_l[r][l] = sqrtf(e / s);
    }
    __syncthreads();

    // ---- Phase 3b: Q assembly (one Q-row per thread, 160 active) ----
    if (tid < 160) {
        const int r = tid / NST;
        const int i = tid % NST;
        const float inv_si = 1.0f / s_l[r][i];
        float q[NST];
        float rowsum = 0.f;
#pragma unroll
        for (int j = 0; j < NST; ++j) {
            if (j == i) { q[j] = 0.f; continue; }
            int a = (i < j) ? i : j;
            int b = (i < j) ? j : i;
            int idx = a * NST - a * (a + 1) / 2 + (b - a - 1);
            float v = sp_l[r][idx] * s_l[r][j] * inv_si;
            q[j] = v;
            rowsum += v;
        }
        q[i] = -rowsum;
        float* dst = Out + (size_t)(g0 + r) * (NST * NST) + i * NST;
#pragma unroll
        for (int j4 = 0; j4 < 5; ++j4) {
            *(float4*)(dst + j4 * 4) =
                make_float4(q[j4 * 4], q[j4 * 4 + 1], q[j4 * 4 + 2], q[j4 * 4 + 3]);
        }
    }
}

extern "C" void kernel_launch(void* const* d_in, const int* in_sizes, int n_in,
                              void* d_out, int out_size, void* d_ws, size_t ws_size,
                              hipStream_t stream) {
    const float* hx      = (const float*)d_in[0];
    const float* dense_w = (const float*)d_in[1];
    const float* dense_b = (const float*)d_in[2];
    const float* ln_w    = (const float*)d_in[3];
    const float* ln_b    = (const float*)d_in[4];
    const float* theta_w = (const float*)d_in[5];
    const float* theta_b = (const float*)d_in[6];
    const float* Theta_w = (const float*)d_in[7];
    const float* Theta_b = (const float*)d_in[8];
    float* out = (float*)d_out;

    float* H = (float*)d_ws;  // needs NTOK*D*4 = 41.9 MB

    dim3 gridA(NTOK / BM, D / BN);
    gemm_gelu_kernel<<<gridA, 256, 0, stream>>>(hx, dense_w, dense_b, H);

    head_kernel<<<NTOK / 8, 256, 0, stream>>>(H, ln_w, ln_b, theta_w, theta_b,
                                              Theta_w, Theta_b, out);
}

// Round 2
// 281.334 us; speedup vs baseline: 2.1070x; 2.1070x over previous
//
#include <hip/hip_runtime.h>
#include <hip/hip_bf16.h>
#include <math.h>

#define D 1280
#define NST 20
#define MTRI 190
#define NTOK 8192   // B*L

typedef __attribute__((ext_vector_type(4))) float f32x4;
typedef __attribute__((ext_vector_type(8))) __bf16 bf16x8;
typedef __attribute__((ext_vector_type(8))) unsigned short ushort8;

__device__ __forceinline__ void gload_lds16(const void* g, void* l) {
    __builtin_amdgcn_global_load_lds(
        (const __attribute__((address_space(1))) void*)g,
        (__attribute__((address_space(3))) void*)l, 16, 0, 0);
}

__device__ __forceinline__ unsigned short f2bf(float x) {
    __hip_bfloat16 b = __float2bfloat16(x);
    return __builtin_bit_cast(unsigned short, b);
}

// ---------- Kernel 0: Wt[n][k] = bf16(dense_w[k][n]) ----------
__global__ __launch_bounds__(256) void transpose_w_kernel(
    const float* __restrict__ W, unsigned short* __restrict__ Wt)
{
    __shared__ float t[64][65];
    const int tid = threadIdx.x;
    const int k0 = blockIdx.x * 64, n0 = blockIdx.y * 64;
#pragma unroll
    for (int i = 0; i < 16; ++i) {
        int lin = i * 256 + tid;
        int r = lin >> 6, c = lin & 63;
        t[r][c] = W[(size_t)(k0 + r) * D + n0 + c];
    }
    __syncthreads();
#pragma unroll
    for (int i = 0; i < 16; ++i) {
        int lin = i * 256 + tid;
        int r = lin >> 6, c = lin & 63;
        Wt[(size_t)(n0 + r) * D + (k0 + c)] = f2bf(t[c][r]);
    }
}

// ---------- Kernel A: H = gelu(hx @ dense_w + dense_b), bf16 MFMA ----------
// 128x128 tile, BK=32, 4 waves (2x2), 4x4 16x16x32 frags per wave.
#define BK 32

__global__ __launch_bounds__(256) void gemm_gelu_mfma_kernel(
    const float* __restrict__ A,           // [NTOK, D] f32
    const unsigned short* __restrict__ Wt, // [D(n), D(k)] bf16 bits
    const float* __restrict__ bias,        // [D]
    float* __restrict__ H)                 // [NTOK, D] f32
{
    __shared__ unsigned short As[128 * BK]; // [row][k] 8 KB
    __shared__ unsigned short Bs[128 * BK]; // [n][k]   8 KB

    const int tid  = threadIdx.x;
    const int lane = tid & 63;
    const int w    = tid >> 6;      // wave 0..3
    const int wr   = w >> 1;        // wave row 0..1
    const int wc   = w & 1;         // wave col 0..1

    const int col0 = blockIdx.x * 128;  // over N=1280 (10 tiles)
    const int row0 = blockIdx.y * 128;  // over M=8192 (64 tiles)

    f32x4 acc[4][4];
#pragma unroll
    for (int m = 0; m < 4; ++m)
#pragma unroll
        for (int n = 0; n < 4; ++n) acc[m][n] = (f32x4)0.0f;

    // A staging assignment: thread -> half row (16 floats)
    const int aRow = tid >> 1;
    const int aK   = (tid & 1) * 16;
    const float* aBase = &A[(size_t)(row0 + aRow) * D + aK];

    // B staging: global_load_lds, wave-uniform LDS base
    const int bN  = (lane >> 2);        // 0..15 within 16-row group
    const int bK8 = (lane & 3) * 8;

    const int fr = lane & 15;       // fragment row/col
    const int fk = (lane >> 4) * 8; // fragment k offset

    for (int k0 = 0; k0 < D; k0 += BK) {
        // ---- stage B via async global->LDS (2 x 4096B issues) ----
#pragma unroll
        for (int p = 0; p < 2; ++p) {
            const int ng = p * 64 + w * 16;   // wave's 16-row group
            const unsigned short* g =
                &Wt[(size_t)(col0 + ng + bN) * D + k0 + bK8];
            unsigned short* lb = &Bs[ng * BK];  // wave-uniform
            gload_lds16(g, lb);
        }
        // ---- stage A: load 16 f32, convert, 2x ds_write_b128 ----
        {
            const float4 f0 = *(const float4*)(aBase + k0 + 0);
            const float4 f1 = *(const float4*)(aBase + k0 + 4);
            const float4 f2 = *(const float4*)(aBase + k0 + 8);
            const float4 f3 = *(const float4*)(aBase + k0 + 12);
            ushort8 u0, u1;
            u0[0] = f2bf(f0.x); u0[1] = f2bf(f0.y); u0[2] = f2bf(f0.z); u0[3] = f2bf(f0.w);
            u0[4] = f2bf(f1.x); u0[5] = f2bf(f1.y); u0[6] = f2bf(f1.z); u0[7] = f2bf(f1.w);
            u1[0] = f2bf(f2.x); u1[1] = f2bf(f2.y); u1[2] = f2bf(f2.z); u1[3] = f2bf(f2.w);
            u1[4] = f2bf(f3.x); u1[5] = f2bf(f3.y); u1[6] = f2bf(f3.z); u1[7] = f2bf(f3.w);
            *(ushort8*)&As[aRow * BK + aK]     = u0;
            *(ushort8*)&As[aRow * BK + aK + 8] = u1;
        }
        __syncthreads();

        // ---- fragments + MFMA ----
        bf16x8 af[4], bfv[4];
#pragma unroll
        for (int m = 0; m < 4; ++m)
            af[m] = *(const bf16x8*)&As[(wr * 64 + m * 16 + fr) * BK + fk];
#pragma unroll
        for (int n = 0; n < 4; ++n)
            bfv[n] = *(const bf16x8*)&Bs[(wc * 64 + n * 16 + fr) * BK + fk];
#pragma unroll
        for (int m = 0; m < 4; ++m)
#pragma unroll
            for (int n = 0; n < 4; ++n)
                acc[m][n] = __builtin_amdgcn_mfma_f32_16x16x32_bf16(
                    af[m], bfv[n], acc[m][n], 0, 0, 0);
        __syncthreads();
    }

    // ---- epilogue: bias + exact gelu, f32 store ----
    const int crow = (lane >> 4) * 4;  // C/D: row=(lane>>4)*4+reg, col=lane&15
#pragma unroll
    for (int n = 0; n < 4; ++n) {
        const int col = col0 + wc * 64 + n * 16 + fr;
        const float bv = bias[col];
#pragma unroll
        for (int m = 0; m < 4; ++m) {
            const int rbase = row0 + wr * 64 + m * 16 + crow;
#pragma unroll
            for (int r = 0; r < 4; ++r) {
                float h = acc[m][n][r] + bv;
                float g = 0.5f * h * (1.0f + erff(h * 0.70710678118654752f));
                H[(size_t)(rbase + r) * D + col] = g;
            }
        }
    }
}

// ---------------- Kernel B: LN + logits + softmax/softplus + Q assembly -----
__global__ __launch_bounds__(256) void head_kernel(
    const float* __restrict__ H,
    const float* __restrict__ ln_w, const float* __restrict__ ln_b,
    const float* __restrict__ theta_w, const float* __restrict__ theta_b,
    const float* __restrict__ Theta_w, const float* __restrict__ Theta_b,
    float* __restrict__ Out)
{
    __shared__ float hn[8][D];        // 40 KB normalized rows
    __shared__ float th_l[8][NST];
    __shared__ float sp_l[8][MTRI];
    __shared__ float s_l[8][NST];

    const int tid  = threadIdx.x;
    const int lane = tid & 63;
    const int wave = tid >> 6;
    const int g0   = blockIdx.x * 8;

    // ---- Phase 1: LayerNorm (per wave: 2 rows) ----
#pragma unroll
    for (int rr = 0; rr < 2; ++rr) {
        const int r = wave * 2 + rr;
        const float* src = H + (size_t)(g0 + r) * D;
        float x[20];
        float sum = 0.f, sq = 0.f;
#pragma unroll
        for (int it = 0; it < 20; ++it) {
            float v = src[lane + it * 64];
            x[it] = v; sum += v; sq += v * v;
        }
#pragma unroll
        for (int off = 1; off < 64; off <<= 1) {
            sum += __shfl_xor(sum, off);
            sq  += __shfl_xor(sq, off);
        }
        const float mean = sum * (1.0f / D);
        const float var  = sq * (1.0f / D) - mean * mean;
        const float inv  = rsqrtf(var + 1e-5f);
#pragma unroll
        for (int it = 0; it < 20; ++it) {
            int k = lane + it * 64;
            hn[r][k] = (x[it] - mean) * inv * ln_w[k] + ln_b[k];
        }
    }
    __syncthreads();

    // ---- Phase 2: logits (one column per thread, 210 active) ----
    if (tid < NST + MTRI) {
        const bool isTheta = tid >= NST;
        const int  col     = isTheta ? (tid - NST) : tid;
        const float* W     = isTheta ? (Theta_w + col) : (theta_w + col);
        const int  stride  = isTheta ? MTRI : NST;

        float acc[8] = {0, 0, 0, 0, 0, 0, 0, 0};
        for (int k = 0; k < D; k += 4) {
            float w0 = W[(size_t)(k + 0) * stride];
            float w1 = W[(size_t)(k + 1) * stride];
            float w2 = W[(size_t)(k + 2) * stride];
            float w3 = W[(size_t)(k + 3) * stride];
#pragma unroll
            for (int r = 0; r < 8; ++r) {
                float4 h4 = *(const float4*)&hn[r][k];
                acc[r] += h4.x * w0 + h4.y * w1 + h4.z * w2 + h4.w * w3;
            }
        }
        const float bias = isTheta ? Theta_b[col] : theta_b[col];
#pragma unroll
        for (int r = 0; r < 8; ++r) {
            float v = acc[r] + bias;
            if (isTheta) {
                sp_l[r][col] = (v > 20.0f) ? v : log1pf(expf(v));
            } else {
                th_l[r][col] = v;
            }
        }
    }
    __syncthreads();

    // ---- Phase 3a: softmax -> sqrt(pi), per half-wave row ----
    {
        const int half = lane >> 5;
        const int l    = lane & 31;
        const int r    = wave * 2 + half;
        float v = (l < NST) ? th_l[r][l] : -1e30f;
        float m = v;
#pragma unroll
        for (int off = 16; off >= 1; off >>= 1) m = fmaxf(m, __shfl_xor(m, off));
        float e = (l < NST) ? __expf(v - m) : 0.0f;
        float s = e;
#pragma unroll
        for (int off = 16; off >= 1; off >>= 1) s += __shfl_xor(s, off);
        if (l < NST) s_l[r][l] = sqrtf(e / s);
    }
    __syncthreads();

    // ---- Phase 3b: Q assembly (one Q-row per thread, 160 active) ----
    if (tid < 160) {
        const int r = tid / NST;
        const int i = tid % NST;
        const float inv_si = 1.0f / s_l[r][i];
        float q[NST];
        float rowsum = 0.f;
#pragma unroll
        for (int j = 0; j < NST; ++j) {
            if (j == i) { q[j] = 0.f; continue; }
            int a = (i < j) ? i : j;
            int b = (i < j) ? j : i;
            int idx = a * NST - a * (a + 1) / 2 + (b - a - 1);
            float v = sp_l[r][idx] * s_l[r][j] * inv_si;
            q[j] = v;
            rowsum += v;
        }
        q[i] = -rowsum;
        float* dst = Out + (size_t)(g0 + r) * (NST * NST) + i * NST;
#pragma unroll
        for (int j4 = 0; j4 < 5; ++j4) {
            *(float4*)(dst + j4 * 4) =
                make_float4(q[j4 * 4], q[j4 * 4 + 1], q[j4 * 4 + 2], q[j4 * 4 + 3]);
        }
    }
}

extern "C" void kernel_launch(void* const* d_in, const int* in_sizes, int n_in,
                              void* d_out, int out_size, void* d_ws, size_t ws_size,
                              hipStream_t stream) {
    const float* hx      = (const float*)d_in[0];
    const float* dense_w = (const float*)d_in[1];
    const float* dense_b = (const float*)d_in[2];
    const float* ln_w    = (const float*)d_in[3];
    const float* ln_b    = (const float*)d_in[4];
    const float* theta_w = (const float*)d_in[5];
    const float* theta_b = (const float*)d_in[6];
    const float* Theta_w = (const float*)d_in[7];
    const float* Theta_b = (const float*)d_in[8];
    float* out = (float*)d_out;

    // ws layout: H f32 [NTOK*D] (41.9 MB) | Wt bf16 [D*D] (3.3 MB)
    float* H = (float*)d_ws;
    unsigned short* Wt = (unsigned short*)((char*)d_ws + (size_t)NTOK * D * 4);

    dim3 gridT(D / 64, D / 64);
    transpose_w_kernel<<<gridT, 256, 0, stream>>>(dense_w, Wt);

    dim3 gridA(D / 128, NTOK / 128);
    gemm_gelu_mfma_kernel<<<gridA, 256, 0, stream>>>(hx, Wt, dense_b, H);

    head_kernel<<<NTOK / 8, 256, 0, stream>>>(H, ln_w, ln_b, theta_w, theta_b,
                                              Theta_w, Theta_b, out);
}

// Round 3
// 177.577 us; speedup vs baseline: 3.3382x; 1.5843x over previous
//
#include <hip/hip_runtime.h>
#include <hip/hip_bf16.h>
#include <math.h>

#define D 1280
#define NST 20
#define MTRI 190
#define NTOK 8192   // B*L
#define NC 256      // padded logit columns (20 theta + 190 Theta + 46 zero)

typedef __attribute__((ext_vector_type(4))) float f32x4;
typedef __attribute__((ext_vector_type(8))) __bf16 bf16x8;
typedef __attribute__((ext_vector_type(8))) unsigned short ushort8;

__device__ __forceinline__ void gload_lds16(const void* g, void* l) {
    __builtin_amdgcn_global_load_lds(
        (const __attribute__((address_space(1))) void*)g,
        (__attribute__((address_space(3))) void*)l, 16, 0, 0);
}

__device__ __forceinline__ unsigned short f2bf(float x) {
    __hip_bfloat16 b = __float2bfloat16(x);
    return __builtin_bit_cast(unsigned short, b);
}
__device__ __forceinline__ float bf2f(unsigned short u) {
    unsigned int x = ((unsigned int)u) << 16;
    return __builtin_bit_cast(float, x);
}

// ---------- Kernel 0a: Wt[n][k] = bf16(dense_w[k][n]) ----------
__global__ __launch_bounds__(256) void transpose_w_kernel(
    const float* __restrict__ W, unsigned short* __restrict__ Wt)
{
    __shared__ float t[64][65];
    const int tid = threadIdx.x;
    const int k0 = blockIdx.x * 64, n0 = blockIdx.y * 64;
#pragma unroll
    for (int i = 0; i < 16; ++i) {
        int lin = i * 256 + tid;
        int r = lin >> 6, c = lin & 63;
        t[r][c] = W[(size_t)(k0 + r) * D + n0 + c];
    }
    __syncthreads();
#pragma unroll
    for (int i = 0; i < 16; ++i) {
        int lin = i * 256 + tid;
        int r = lin >> 6, c = lin & 63;
        Wt[(size_t)(n0 + r) * D + (k0 + c)] = f2bf(t[c][r]);
    }
}

// ---------- Kernel 0b: Wcat[col][k], col 0..19 theta, 20..209 Theta, pad 0 --
__global__ __launch_bounds__(256) void build_wcat_kernel(
    const float* __restrict__ theta_w, const float* __restrict__ Theta_w,
    unsigned short* __restrict__ Wcat)
{
    const int col = threadIdx.x;          // 0..255
    const int k0  = blockIdx.x * 64;      // 20 blocks
    for (int kk = 0; kk < 64; kk += 8) {
        ushort8 u;
#pragma unroll
        for (int j = 0; j < 8; ++j) {
            int k = k0 + kk + j;
            float v = 0.0f;
            if (col < NST)            v = theta_w[(size_t)k * NST + col];
            else if (col < NST + MTRI) v = Theta_w[(size_t)k * MTRI + (col - NST)];
            u[j] = f2bf(v);
        }
        *(ushort8*)&Wcat[(size_t)col * D + k0 + kk] = u;
    }
}

// ---------- Kernel A: H = gelu(hx @ dense_w + dense_b), bf16 out ----------
#define BK 32

__global__ __launch_bounds__(256) void gemm_gelu_mfma_kernel(
    const float* __restrict__ A,           // [NTOK, D] f32
    const unsigned short* __restrict__ Wt, // [D(n), D(k)] bf16 bits
    const float* __restrict__ bias,        // [D]
    unsigned short* __restrict__ H)        // [NTOK, D] bf16 bits
{
    __shared__ unsigned short As[128 * BK];
    __shared__ unsigned short Bs[128 * BK];

    const int tid  = threadIdx.x;
    const int lane = tid & 63;
    const int w    = tid >> 6;
    const int wr   = w >> 1;
    const int wc   = w & 1;

    const int col0 = blockIdx.x * 128;
    const int row0 = blockIdx.y * 128;

    f32x4 acc[4][4];
#pragma unroll
    for (int m = 0; m < 4; ++m)
#pragma unroll
        for (int n = 0; n < 4; ++n) acc[m][n] = (f32x4)0.0f;

    const int aRow = tid >> 1;
    const int aK   = (tid & 1) * 16;
    const float* aBase = &A[(size_t)(row0 + aRow) * D + aK];

    const int bN  = (lane >> 2);
    const int bK8 = (lane & 3) * 8;

    const int fr = lane & 15;
    const int fk = (lane >> 4) * 8;

    for (int k0 = 0; k0 < D; k0 += BK) {
#pragma unroll
        for (int p = 0; p < 2; ++p) {
            const int ng = p * 64 + w * 16;
            const unsigned short* g =
                &Wt[(size_t)(col0 + ng + bN) * D + k0 + bK8];
            unsigned short* lb = &Bs[ng * BK];
            gload_lds16(g, lb);
        }
        {
            const float4 f0 = *(const float4*)(aBase + k0 + 0);
            const float4 f1 = *(const float4*)(aBase + k0 + 4);
            const float4 f2 = *(const float4*)(aBase + k0 + 8);
            const float4 f3 = *(const float4*)(aBase + k0 + 12);
            ushort8 u0, u1;
            u0[0] = f2bf(f0.x); u0[1] = f2bf(f0.y); u0[2] = f2bf(f0.z); u0[3] = f2bf(f0.w);
            u0[4] = f2bf(f1.x); u0[5] = f2bf(f1.y); u0[6] = f2bf(f1.z); u0[7] = f2bf(f1.w);
            u1[0] = f2bf(f2.x); u1[1] = f2bf(f2.y); u1[2] = f2bf(f2.z); u1[3] = f2bf(f2.w);
            u1[4] = f2bf(f3.x); u1[5] = f2bf(f3.y); u1[6] = f2bf(f3.z); u1[7] = f2bf(f3.w);
            *(ushort8*)&As[aRow * BK + aK]     = u0;
            *(ushort8*)&As[aRow * BK + aK + 8] = u1;
        }
        __syncthreads();

        bf16x8 af[4], bfv[4];
#pragma unroll
        for (int m = 0; m < 4; ++m)
            af[m] = *(const bf16x8*)&As[(wr * 64 + m * 16 + fr) * BK + fk];
#pragma unroll
        for (int n = 0; n < 4; ++n)
            bfv[n] = *(const bf16x8*)&Bs[(wc * 64 + n * 16 + fr) * BK + fk];
#pragma unroll
        for (int m = 0; m < 4; ++m)
#pragma unroll
            for (int n = 0; n < 4; ++n)
                acc[m][n] = __builtin_amdgcn_mfma_f32_16x16x32_bf16(
                    af[m], bfv[n], acc[m][n], 0, 0, 0);
        __syncthreads();
    }

    const int crow = (lane >> 4) * 4;
#pragma unroll
    for (int n = 0; n < 4; ++n) {
        const int col = col0 + wc * 64 + n * 16 + fr;
        const float bv = bias[col];
#pragma unroll
        for (int m = 0; m < 4; ++m) {
            const int rbase = row0 + wr * 64 + m * 16 + crow;
#pragma unroll
            for (int r = 0; r < 4; ++r) {
                float h = acc[m][n][r] + bv;
                float g = 0.5f * h * (1.0f + erff(h * 0.70710678118654752f));
                H[(size_t)(rbase + r) * D + col] = f2bf(g);
            }
        }
    }
}

// ---------- Kernel C: fused LN + logits MFMA + softmax/softplus + Q ----------
// 32 rows/block, 256 threads (4 waves), grid = NTOK/32 = 256.
__global__ __launch_bounds__(256) void head_mfma_kernel(
    const unsigned short* __restrict__ Hb,   // [NTOK, D] bf16
    const float* __restrict__ ln_w, const float* __restrict__ ln_b,
    const float* __restrict__ theta_b, const float* __restrict__ Theta_b,
    const unsigned short* __restrict__ Wcat, // [NC, D] bf16
    float* __restrict__ Out)                 // [NTOK, 400]
{
    __shared__ float lnw_s[D], lnb_s[D];
    __shared__ float biascat[NC];
    __shared__ float mean_s[32], inv_s[32];
    // union: GEMM staging (As 2KB + Bs 16KB) vs post arrays (29.4KB)
    __shared__ __align__(16) char uni[32 * NST * 4 + 32 * MTRI * 4 + 32 * NST * 4];
    unsigned short* As = (unsigned short*)uni;            // [32][32]
    unsigned short* Bs = (unsigned short*)(uni + 2048);   // [256][32]
    float (*th_l)[NST]  = (float (*)[NST])uni;
    float (*sp_l)[MTRI] = (float (*)[MTRI])(uni + 32 * NST * 4);
    float (*s_l)[NST]   = (float (*)[NST])(uni + 32 * NST * 4 + 32 * MTRI * 4);

    const int tid  = threadIdx.x;
    const int lane = tid & 63;
    const int wave = tid >> 6;
    const int g0   = blockIdx.x * 32;

    // ---- preload ln params + bias ----
#pragma unroll
    for (int i = 0; i < 5; ++i) {
        int k = i * 256 + tid;
        lnw_s[k] = ln_w[k];
        lnb_s[k] = ln_b[k];
    }
    {
        float v = 0.0f;
        if (tid < NST) v = theta_b[tid];
        else if (tid < NST + MTRI) v = Theta_b[tid - NST];
        biascat[tid] = v;
    }

    // ---- pass 1: LN stats for 8 rows per wave ----
#pragma unroll
    for (int rr = 0; rr < 8; ++rr) {
        const int r = wave * 8 + rr;
        const unsigned short* src = Hb + (size_t)(g0 + r) * D;
        float sum = 0.f, sq = 0.f;
#pragma unroll
        for (int it = 0; it < 3; ++it) {
            int c = it * 64 + lane;
            if (c < 160) {
                ushort8 u = *(const ushort8*)(src + c * 8);
#pragma unroll
                for (int j = 0; j < 8; ++j) {
                    float f = bf2f(u[j]);
                    sum += f; sq += f * f;
                }
            }
        }
#pragma unroll
        for (int off = 1; off < 64; off <<= 1) {
            sum += __shfl_xor(sum, off);
            sq  += __shfl_xor(sq, off);
        }
        if (lane == 0) {
            float mean = sum * (1.0f / D);
            float var  = sq * (1.0f / D) - mean * mean;
            mean_s[r] = mean;
            inv_s[r]  = rsqrtf(var + 1e-5f);
        }
    }
    __syncthreads();

    // ---- GEMM: logits[32][256] = hn @ Wcat^T ----
    const int fr = lane & 15;
    const int fk = (lane >> 4) * 8;
    f32x4 acc[2][4];
#pragma unroll
    for (int m = 0; m < 2; ++m)
#pragma unroll
        for (int n = 0; n < 4; ++n) acc[m][n] = (f32x4)0.0f;

    const int aRow = tid >> 2;        // 0..63 used when tid<128 -> rows 0..31
    const int aK   = (tid & 3) * 8;

    for (int k0 = 0; k0 < D; k0 += 32) {
        // stage B: 4 issues per wave, 16 cols each
#pragma unroll
        for (int i = 0; i < 4; ++i) {
            const int c0  = wave * 64 + i * 16;
            const int col = c0 + (lane >> 2);
            const unsigned short* g = &Wcat[(size_t)col * D + k0 + (lane & 3) * 8];
            gload_lds16(g, &Bs[c0 * 32]);
        }
        // stage A (normalized on the fly): threads 0..127
        if (tid < 128) {
            const int row = aRow;     // 0..31
            const float mean = mean_s[row];
            const float inv  = inv_s[row];
            ushort8 u = *(const ushort8*)(Hb + (size_t)(g0 + row) * D + k0 + aK);
            ushort8 o;
#pragma unroll
            for (int j = 0; j < 8; ++j) {
                int k = k0 + aK + j;
                float v = (bf2f(u[j]) - mean) * inv * lnw_s[k] + lnb_s[k];
                o[j] = f2bf(v);
            }
            *(ushort8*)&As[row * 32 + aK] = o;
        }
        __syncthreads();

        bf16x8 af[2], bfv[4];
#pragma unroll
        for (int m = 0; m < 2; ++m)
            af[m] = *(const bf16x8*)&As[(m * 16 + fr) * 32 + fk];
#pragma unroll
        for (int n = 0; n < 4; ++n)
            bfv[n] = *(const bf16x8*)&Bs[(wave * 64 + n * 16 + fr) * 32 + fk];
#pragma unroll
        for (int m = 0; m < 2; ++m)
#pragma unroll
            for (int n = 0; n < 4; ++n)
                acc[m][n] = __builtin_amdgcn_mfma_f32_16x16x32_bf16(
                    af[m], bfv[n], acc[m][n], 0, 0, 0);
        __syncthreads();
    }

    // ---- epilogue: logits -> th_l (raw) / sp_l (softplus) ----
    const int crow = (lane >> 4) * 4;
#pragma unroll
    for (int m = 0; m < 2; ++m) {
#pragma unroll
        for (int n = 0; n < 4; ++n) {
            const int col = wave * 64 + n * 16 + fr;
            const float bv = biascat[col];
#pragma unroll
            for (int r = 0; r < 4; ++r) {
                const int row = m * 16 + crow + r;
                float v = acc[m][n][r] + bv;
                if (col < NST) {
                    th_l[row][col] = v;
                } else if (col < NST + MTRI) {
                    sp_l[row][col - NST] = (v > 20.0f) ? v : log1pf(expf(v));
                }
            }
        }
    }
    __syncthreads();

    // ---- softmax -> sqrt(pi): half-wave per row, 8 rows/pass ----
#pragma unroll
    for (int p = 0; p < 4; ++p) {
        const int r = p * 8 + wave * 2 + (lane >> 5);
        const int l = lane & 31;
        float v = (l < NST) ? th_l[r][l] : -1e30f;
        float m = v;
#pragma unroll
        for (int off = 16; off >= 1; off >>= 1) m = fmaxf(m, __shfl_xor(m, off));
        float e = (l < NST) ? __expf(v - m) : 0.0f;
        float s = e;
#pragma unroll
        for (int off = 16; off >= 1; off >>= 1) s += __shfl_xor(s, off);
        if (l < NST) s_l[r][l] = sqrtf(e / s);
    }
    __syncthreads();

    // ---- Q assembly: 640 (row,i) pairs over 256 threads ----
#pragma unroll
    for (int base = 0; base < 640; base += 256) {
        const int idx = base + tid;
        if (idx < 640) {
            const int r = idx / NST;
            const int i = idx % NST;
            const float inv_si = 1.0f / s_l[r][i];
            float q[NST];
            float rowsum = 0.f;
#pragma unroll
            for (int j = 0; j < NST; ++j) {
                if (j == i) { q[j] = 0.f; continue; }
                int a = (i < j) ? i : j;
                int b = (i < j) ? j : i;
                int t = a * NST - a * (a + 1) / 2 + (b - a - 1);
                float v = sp_l[r][t] * s_l[r][j] * inv_si;
                q[j] = v;
                rowsum += v;
            }
            q[i] = -rowsum;
            float* dst = Out + (size_t)(g0 + r) * (NST * NST) + i * NST;
#pragma unroll
            for (int j4 = 0; j4 < 5; ++j4) {
                *(float4*)(dst + j4 * 4) =
                    make_float4(q[j4 * 4], q[j4 * 4 + 1], q[j4 * 4 + 2], q[j4 * 4 + 3]);
            }
        }
    }
}

extern "C" void kernel_launch(void* const* d_in, const int* in_sizes, int n_in,
                              void* d_out, int out_size, void* d_ws, size_t ws_size,
                              hipStream_t stream) {
    const float* hx      = (const float*)d_in[0];
    const float* dense_w = (const float*)d_in[1];
    const float* dense_b = (const float*)d_in[2];
    const float* ln_w    = (const float*)d_in[3];
    const float* ln_b    = (const float*)d_in[4];
    const float* theta_w = (const float*)d_in[5];
    const float* theta_b = (const float*)d_in[6];
    const float* Theta_w = (const float*)d_in[7];
    const float* Theta_b = (const float*)d_in[8];
    float* out = (float*)d_out;

    // ws: H bf16 [NTOK*D] 21MB | Wt bf16 [D*D] 3.3MB | Wcat bf16 [NC*D] 0.66MB
    unsigned short* H    = (unsigned short*)d_ws;
    unsigned short* Wt   = H + (size_t)NTOK * D;
    unsigned short* Wcat = Wt + (size_t)D * D;

    dim3 gridT(D / 64, D / 64);
    transpose_w_kernel<<<gridT, 256, 0, stream>>>(dense_w, Wt);
    build_wcat_kernel<<<D / 64, 256, 0, stream>>>(theta_w, Theta_w, Wcat);

    dim3 gridA(D / 128, NTOK / 128);
    gemm_gelu_mfma_kernel<<<gridA, 256, 0, stream>>>(hx, Wt, dense_b, H);

    head_mfma_kernel<<<NTOK / 32, 256, 0, stream>>>(H, ln_w, ln_b, theta_b,
                                                    Theta_b, Wcat, out);
}

// Round 5
// 124.062 us; speedup vs baseline: 4.7781x; 1.4314x over previous
//
#include <hip/hip_runtime.h>
#include <hip/hip_bf16.h>
#include <math.h>

#define D 1280
#define NST 20
#define MTRI 190
#define NTOK 8192   // B*L
#define NC 256      // padded logit columns

typedef __attribute__((ext_vector_type(4))) float f32x4;
typedef __attribute__((ext_vector_type(8))) __bf16 bf16x8;
typedef __attribute__((ext_vector_type(8))) unsigned short ushort8;
typedef __attribute__((ext_vector_type(4))) unsigned short bfu4;

__device__ __forceinline__ void gload_lds16(const void* g, void* l) {
    __builtin_amdgcn_global_load_lds(
        (const __attribute__((address_space(1))) void*)g,
        (__attribute__((address_space(3))) void*)l, 16, 0, 0);
}

__device__ __forceinline__ unsigned short f2bf(float x) {
    __hip_bfloat16 b = __float2bfloat16(x);
    return __builtin_bit_cast(unsigned short, b);
}
__device__ __forceinline__ float bf2f(unsigned short u) {
    unsigned int x = ((unsigned int)u) << 16;
    return __builtin_bit_cast(float, x);
}

// ---------- Kernel P0: hx f32 -> bf16 ----------
__global__ __launch_bounds__(256) void tobf_kernel(
    const float* __restrict__ X, unsigned short* __restrict__ Y)
{
    const size_t i = ((size_t)blockIdx.x * 256 + threadIdx.x) * 8;
    float4 a = *(const float4*)(X + i);
    float4 b = *(const float4*)(X + i + 4);
    ushort8 u;
    u[0] = f2bf(a.x); u[1] = f2bf(a.y); u[2] = f2bf(a.z); u[3] = f2bf(a.w);
    u[4] = f2bf(b.x); u[5] = f2bf(b.y); u[6] = f2bf(b.z); u[7] = f2bf(b.w);
    *(ushort8*)(Y + i) = u;
}

// ---------- Kernel P1: Wt[n][k] = bf16(dense_w[k][n]) ----------
__global__ __launch_bounds__(256) void transpose_w_kernel(
    const float* __restrict__ W, unsigned short* __restrict__ Wt)
{
    __shared__ float t[64][65];
    const int tid = threadIdx.x;
    const int k0 = blockIdx.x * 64, n0 = blockIdx.y * 64;
#pragma unroll
    for (int i = 0; i < 16; ++i) {
        int lin = i * 256 + tid;
        int r = lin >> 6, c = lin & 63;
        t[r][c] = W[(size_t)(k0 + r) * D + n0 + c];
    }
    __syncthreads();
#pragma unroll
    for (int i = 0; i < 16; ++i) {
        int lin = i * 256 + tid;
        int r = lin >> 6, c = lin & 63;
        Wt[(size_t)(n0 + r) * D + (k0 + c)] = f2bf(t[c][r]);
    }
}

// ---------- Kernel P2: Wcat[col][k] ----------
__global__ __launch_bounds__(256) void build_wcat_kernel(
    const float* __restrict__ theta_w, const float* __restrict__ Theta_w,
    unsigned short* __restrict__ Wcat)
{
    const int col = threadIdx.x;          // 0..255
    const int k0  = blockIdx.x * 64;      // 20 blocks
    for (int kk = 0; kk < 64; kk += 8) {
        ushort8 u;
#pragma unroll
        for (int j = 0; j < 8; ++j) {
            int k = k0 + kk + j;
            float v = 0.0f;
            if (col < NST)             v = theta_w[(size_t)k * NST + col];
            else if (col < NST + MTRI) v = Theta_w[(size_t)k * MTRI + (col - NST)];
            u[j] = f2bf(v);
        }
        *(ushort8*)&Wcat[(size_t)col * D + k0 + kk] = u;
    }
}

// ---------- Kernel A: H = gelu(hxb @ dense_w + b), bf16 in/out, dbuf ----------
#define BKA 32

__global__ __launch_bounds__(256) void gemm_gelu_mfma_kernel(
    const unsigned short* __restrict__ Ab,  // [NTOK, D] bf16
    const unsigned short* __restrict__ Wt,  // [D(n), D(k)] bf16
    const float* __restrict__ bias,
    unsigned short* __restrict__ H)         // [NTOK, D] bf16
{
    __shared__ unsigned short As[2][128 * BKA];  // 2 x 8 KB
    __shared__ unsigned short Bs[2][128 * BKA];  // 2 x 8 KB

    const int tid  = threadIdx.x;
    const int lane = tid & 63;
    const int w    = tid >> 6;
    const int wr   = w >> 1;
    const int wc   = w & 1;

    // XCD-bijective swizzle: 640 blocks = 8 x 80
    const int bid = blockIdx.x;
    const int swz = (bid & 7) * 80 + (bid >> 3);
    const int row0 = (swz / 10) * 128;
    const int col0 = (swz % 10) * 128;

    f32x4 acc[4][4];
#pragma unroll
    for (int m = 0; m < 4; ++m)
#pragma unroll
        for (int n = 0; n < 4; ++n) acc[m][n] = (f32x4)0.0f;

    // staging: issue covers 16 rows x 32 k; lane -> row (l>>2), k (l&3)*8
    const int sR = lane >> 2;
    const int sK = (lane & 3) * 8;
    const unsigned short* aSrc = &Ab[(size_t)(row0 + w * 16 + sR) * D + sK];
    const unsigned short* bSrc = &Wt[(size_t)(col0 + w * 16 + sR) * D + sK];

    auto STAGE = [&](int b, int k0) {
#pragma unroll
        for (int p = 0; p < 2; ++p) {
            gload_lds16(aSrc + (size_t)(p * 64) * D + k0, &As[b][(p * 64 + w * 16) * BKA]);
            gload_lds16(bSrc + (size_t)(p * 64) * D + k0, &Bs[b][(p * 64 + w * 16) * BKA]);
        }
    };

    STAGE(0, 0);
    __syncthreads();

    const int fr = lane & 15;
    const int fk = (lane >> 4) * 8;

    for (int t = 0; t < 40; ++t) {
        const int cur = t & 1;
        if (t < 39) STAGE(cur ^ 1, (t + 1) * BKA);

        bf16x8 af[4], bfv[4];
#pragma unroll
        for (int m = 0; m < 4; ++m)
            af[m] = *(const bf16x8*)&As[cur][(wr * 64 + m * 16 + fr) * BKA + fk];
#pragma unroll
        for (int n = 0; n < 4; ++n)
            bfv[n] = *(const bf16x8*)&Bs[cur][(wc * 64 + n * 16 + fr) * BKA + fk];
#pragma unroll
        for (int m = 0; m < 4; ++m)
#pragma unroll
            for (int n = 0; n < 4; ++n)
                acc[m][n] = __builtin_amdgcn_mfma_f32_16x16x32_bf16(
                    af[m], bfv[n], acc[m][n], 0, 0, 0);
        __syncthreads();
    }

    const int crow = (lane >> 4) * 4;
#pragma unroll
    for (int n = 0; n < 4; ++n) {
        const int col = col0 + wc * 64 + n * 16 + fr;
        const float bv = bias[col];
#pragma unroll
        for (int m = 0; m < 4; ++m) {
            const int rbase = row0 + wr * 64 + m * 16 + crow;
#pragma unroll
            for (int r = 0; r < 4; ++r) {
                float h = acc[m][n][r] + bv;
                float g = 0.5f * h * (1.0f + erff(h * 0.70710678118654752f));
                H[(size_t)(rbase + r) * D + col] = f2bf(g);
            }
        }
    }
}

// ---------- Kernel S: per-row LN stats (mean, rstd) ----------
__global__ __launch_bounds__(256) void ln_stats_kernel(
    const unsigned short* __restrict__ Hb, float2* __restrict__ stats)
{
    const int wave = threadIdx.x >> 6, lane = threadIdx.x & 63;
    const int row = blockIdx.x * 4 + wave;
    const unsigned short* src = Hb + (size_t)row * D;
    float sum = 0.f, sq = 0.f;
#pragma unroll
    for (int i = 0; i < 5; ++i) {
        bfu4 u = *(const bfu4*)(src + (size_t)(i * 64 + lane) * 4);
#pragma unroll
        for (int j = 0; j < 4; ++j) {
            float f = bf2f(u[j]);
            sum += f; sq += f * f;
        }
    }
#pragma unroll
    for (int off = 1; off < 64; off <<= 1) {
        sum += __shfl_xor(sum, off);
        sq  += __shfl_xor(sq, off);
    }
    if (lane == 0) {
        float mean = sum * (1.0f / D);
        float var  = sq * (1.0f / D) - mean * mean;
        stats[row] = make_float2(mean, rsqrtf(var + 1e-5f));
    }
}

// ---------- Kernel C: fused LN-apply + logits MFMA + softmax/softplus + Q ----
// 16 rows/block, 512 blocks, 4 waves, 2-phase dbuf.
__global__ __launch_bounds__(256) void head_mfma_kernel(
    const unsigned short* __restrict__ Hb,
    const float2* __restrict__ stats,
    const float* __restrict__ ln_w, const float* __restrict__ ln_b,
    const float* __restrict__ theta_b, const float* __restrict__ Theta_b,
    const unsigned short* __restrict__ Wcat,
    float* __restrict__ Out)
{
    __shared__ unsigned short Bs[2][NC * 32];   // 2 x 16 KB
    __shared__ unsigned short As[2][16 * 32];   // 2 x 1 KB
    __shared__ float lnw_s[D], lnb_s[D];        // 10 KB
    __shared__ float biascat[NC];               // 1 KB
    __shared__ float mean_s[16], inv_s[16];
    // post-GEMM arrays alias Bs[0] (14.4 KB <= 16 KB)
    float (*th_l)[NST]  = (float (*)[NST])&Bs[0][0];
    float (*sp_l)[MTRI] = (float (*)[MTRI])((char*)&Bs[0][0] + 16 * NST * 4);
    float (*s_l)[NST]   = (float (*)[NST])((char*)&Bs[0][0] + 16 * NST * 4 + 16 * MTRI * 4);

    const int tid  = threadIdx.x;
    const int lane = tid & 63;
    const int wave = tid >> 6;
    const int bid  = blockIdx.x;
    const int swz  = (bid & 7) * 64 + (bid >> 3);   // 512 = 8 x 64
    const int g0   = swz * 16;

#pragma unroll
    for (int i = 0; i < 5; ++i) {
        int k = i * 256 + tid;
        lnw_s[k] = ln_w[k];
        lnb_s[k] = ln_b[k];
    }
    {
        float v = 0.0f;
        if (tid < NST) v = theta_b[tid];
        else if (tid < NST + MTRI) v = Theta_b[tid - NST];
        biascat[tid] = v;
    }
    if (tid < 16) {
        float2 s = stats[g0 + tid];
        mean_s[tid] = s.x;
        inv_s[tid]  = s.y;
    }
    __syncthreads();

    auto STAGEB = [&](int b, int k0) {
#pragma unroll
        for (int i = 0; i < 4; ++i) {
            const int c0 = wave * 64 + i * 16;
            gload_lds16(&Wcat[(size_t)(c0 + (lane >> 2)) * D + k0 + (lane & 3) * 8],
                        &Bs[b][c0 * 32]);
        }
    };
    auto STAGEA = [&](int b, int k0) {
        if (lane < 16) {
            const int row = wave * 4 + (lane >> 2);
            const int k8  = (lane & 3) * 8;
            const float mean = mean_s[row], inv = inv_s[row];
            ushort8 u = *(const ushort8*)(Hb + (size_t)(g0 + row) * D + k0 + k8);
            ushort8 o;
#pragma unroll
            for (int j = 0; j < 8; ++j) {
                int k = k0 + k8 + j;
                o[j] = f2bf((bf2f(u[j]) - mean) * inv * lnw_s[k] + lnb_s[k]);
            }
            *(ushort8*)&As[b][row * 32 + k8] = o;
        }
    };

    STAGEB(0, 0);
    STAGEA(0, 0);
    __syncthreads();

    f32x4 acc[4];
#pragma unroll
    for (int n = 0; n < 4; ++n) acc[n] = (f32x4)0.0f;

    const int fr = lane & 15;
    const int fk = (lane >> 4) * 8;

    for (int t = 0; t < 40; ++t) {
        const int cur = t & 1;
        if (t < 39) {
            STAGEB(cur ^ 1, (t + 1) * 32);
            STAGEA(cur ^ 1, (t + 1) * 32);
        }
        bf16x8 af = *(const bf16x8*)&As[cur][fr * 32 + fk];
#pragma unroll
        for (int n = 0; n < 4; ++n) {
            bf16x8 bfv = *(const bf16x8*)&Bs[cur][(wave * 64 + n * 16 + fr) * 32 + fk];
            acc[n] = __builtin_amdgcn_mfma_f32_16x16x32_bf16(af, bfv, acc[n], 0, 0, 0);
        }
        __syncthreads();
    }

    // ---- logits -> th_l / softplus(sp_l) ----
    const int crow = (lane >> 4) * 4;
#pragma unroll
    for (int n = 0; n < 4; ++n) {
        const int col = wave * 64 + n * 16 + fr;
        const float bv = biascat[col];
#pragma unroll
        for (int r = 0; r < 4; ++r) {
            const int row = crow + r;
            float v = acc[n][r] + bv;
            if (col < NST) {
                th_l[row][col] = v;
            } else if (col < NST + MTRI) {
                sp_l[row][col - NST] = (v > 20.0f) ? v : log1pf(expf(v));
            }
        }
    }
    __syncthreads();

    // ---- softmax -> sqrt(pi): half-wave per row ----
#pragma unroll
    for (int p = 0; p < 2; ++p) {
        const int r = p * 8 + wave * 2 + (lane >> 5);
        const int l = lane & 31;
        float v = (l < NST) ? th_l[r][l] : -1e30f;
        float m = v;
#pragma unroll
        for (int off = 16; off >= 1; off >>= 1) m = fmaxf(m, __shfl_xor(m, off));
        float e = (l < NST) ? __expf(v - m) : 0.0f;
        float s = e;
#pragma unroll
        for (int off = 16; off >= 1; off >>= 1) s += __shfl_xor(s, off);
        if (l < NST) s_l[r][l] = sqrtf(e / s);
    }
    __syncthreads();

    // ---- Q assembly: 320 (row,i) pairs ----
#pragma unroll
    for (int base = 0; base < 320; base += 256) {
        const int idx = base + tid;
        if (idx < 320) {
            const int r = idx / NST;
            const int i = idx % NST;
            const float inv_si = 1.0f / s_l[r][i];
            float q[NST];
            float rowsum = 0.f;
#pragma unroll
            for (int j = 0; j < NST; ++j) {
                if (j == i) { q[j] = 0.f; continue; }
                int a = (i < j) ? i : j;
                int b = (i < j) ? j : i;
                int tix = a * NST - a * (a + 1) / 2 + (b - a - 1);
                float v = sp_l[r][tix] * s_l[r][j] * inv_si;
                q[j] = v;
                rowsum += v;
            }
            q[i] = -rowsum;
            float* dst = Out + (size_t)(g0 + r) * (NST * NST) + i * NST;
#pragma unroll
            for (int j4 = 0; j4 < 5; ++j4) {
                *(float4*)(dst + j4 * 4) =
                    make_float4(q[j4 * 4], q[j4 * 4 + 1], q[j4 * 4 + 2], q[j4 * 4 + 3]);
            }
        }
    }
}

extern "C" void kernel_launch(void* const* d_in, const int* in_sizes, int n_in,
                              void* d_out, int out_size, void* d_ws, size_t ws_size,
                              hipStream_t stream) {
    const float* hx      = (const float*)d_in[0];
    const float* dense_w = (const float*)d_in[1];
    const float* dense_b = (const float*)d_in[2];
    const float* ln_w    = (const float*)d_in[3];
    const float* ln_b    = (const float*)d_in[4];
    const float* theta_w = (const float*)d_in[5];
    const float* theta_b = (const float*)d_in[6];
    const float* Theta_w = (const float*)d_in[7];
    const float* Theta_b = (const float*)d_in[8];
    float* out = (float*)d_out;

    // ws: hxb bf16 21MB | H bf16 21MB | Wt bf16 3.3MB | Wcat bf16 0.66MB
    // stats (64KB) reuses hxb region (dead after GEMM A)
    unsigned short* hxb  = (unsigned short*)d_ws;
    unsigned short* H    = hxb + (size_t)NTOK * D;
    unsigned short* Wt   = H + (size_t)NTOK * D;
    unsigned short* Wcat = Wt + (size_t)D * D;
    float2* stats        = (float2*)d_ws;

    tobf_kernel<<<(NTOK * D) / 2048, 256, 0, stream>>>(hx, hxb);

    dim3 gridT(D / 64, D / 64);
    transpose_w_kernel<<<gridT, 256, 0, stream>>>(dense_w, Wt);
    build_wcat_kernel<<<D / 64, 256, 0, stream>>>(theta_w, Theta_w, Wcat);

    gemm_gelu_mfma_kernel<<<640, 256, 0, stream>>>(hxb, Wt, dense_b, H);

    ln_stats_kernel<<<NTOK / 4, 256, 0, stream>>>(H, stats);

    head_mfma_kernel<<<512, 256, 0, stream>>>(H, stats, ln_w, ln_b, theta_b,
                                              Theta_b, Wcat, out);
}